// Round 4
// baseline (168.698 us; speedup 1.0000x reference)
//
#include <hip/hip_runtime.h>
#include <math.h>

#define N_PTS 1024
#define HID   256
#define FEAT  2048

typedef short bf16x8 __attribute__((ext_vector_type(8)));
typedef float f32x4  __attribute__((ext_vector_type(4)));

__device__ inline ushort f2bf(float f) {
    union { float f; unsigned u; } v; v.f = f;
    unsigned r = v.u + 0x7fff + ((v.u >> 16) & 1);   // round-to-nearest-even
    return (ushort)(r >> 16);
}

// ---- prep A: convert features fp32->bf16, zero atomic targets + stats ----
// blocks 0..1023: convert 2048 floats each; 1024..2047: zero 1024 floats each
// of x1/x2/hic; 2048: zero stats region (2560 floats incl tickets).
__global__ __launch_bounds__(256) void prep_a(
    const float* __restrict__ feat, ushort* __restrict__ featbf,
    float* __restrict__ zbase, float* __restrict__ statsz)
{
    const int b = blockIdx.x, tid = threadIdx.x;
    if (b < 1024) {
        const int base = b * 2048 + tid * 8;
        float4 v0 = *(const float4*)&feat[base];
        float4 v1 = *(const float4*)&feat[base + 4];
        ushort4 o0, o1;
        o0.x = f2bf(v0.x); o0.y = f2bf(v0.y); o0.z = f2bf(v0.z); o0.w = f2bf(v0.w);
        o1.x = f2bf(v1.x); o1.y = f2bf(v1.y); o1.z = f2bf(v1.z); o1.w = f2bf(v1.w);
        *(ushort4*)&featbf[base]     = o0;
        *(ushort4*)&featbf[base + 4] = o1;
    } else if (b < 2048) {
        float4 z = make_float4(0.f, 0.f, 0.f, 0.f);
        *(float4*)&zbase[(size_t)(b - 1024) * 1024 + tid * 4] = z;
    } else {
        for (int t = tid; t < 2560; t += 256) statsz[t] = 0.f;
    }
}

// ---- prep B: tiled transpose+convert fp32 [K][256] -> bf16 [n][K] ----
// W1 (128 tiles), W2 (16), We1 top (16), We1 bottom (16): 176 blocks.
__global__ __launch_bounds__(256) void prep_t(
    const float* __restrict__ W1, const float* __restrict__ W2,
    const float* __restrict__ We1, ushort* __restrict__ Wt1,
    ushort* __restrict__ Wt2, ushort* __restrict__ Wt34)
{
    __shared__ ushort T[64 * 72];
    const int b = blockIdx.x, tid = threadIdx.x;
    const float* src; ushort* dst; int Kd, kt, nt;
    if (b < 128)      { src = W1;  dst = Wt1;  Kd = 2048; kt = b >> 2;        nt = b & 3; }
    else if (b < 144) { int q = b - 128; src = W2;  dst = Wt2;  Kd = 256; kt = q >> 2; nt = q & 3; }
    else if (b < 160) { int q = b - 144; src = We1; dst = Wt34; Kd = 256; kt = q >> 2; nt = q & 3; }
    else              { int q = b - 160; src = We1 + 256 * 256; dst = Wt34 + 256 * 256;
                        Kd = 256; kt = q >> 2; nt = q & 3; }
    const int k0 = kt * 64, n0 = nt * 64;
    #pragma unroll
    for (int p = 0; p < 4; p++) {
        const int c = p * 256 + tid, r = c >> 4, q = c & 15;
        float4 v = *(const float4*)&src[(size_t)(k0 + r) * 256 + n0 + q * 4];
        T[(q * 4 + 0) * 72 + r] = f2bf(v.x);
        T[(q * 4 + 1) * 72 + r] = f2bf(v.y);
        T[(q * 4 + 2) * 72 + r] = f2bf(v.z);
        T[(q * 4 + 3) * 72 + r] = f2bf(v.w);
    }
    __syncthreads();
    #pragma unroll
    for (int p = 0; p < 2; p++) {
        const int c = p * 256 + tid, r = c >> 3, q = c & 7;
        *(bf16x8*)&dst[(size_t)(n0 + r) * Kd + k0 + q * 8] = *(bf16x8*)&T[r * 72 + q * 8];
    }
}

// ---- bf16 MFMA GEMM, optional fused BN+ReLU on A; atomic fp32 epilogue ----
// BN=false: A = Abf bf16 [m][lda]. BN=true: A = relu(Afp*scale[k]+shift[k]).
// B = Bt bf16 [n][ldb] (pre-transposed). 64x64 tile, BK=64, split-K on z.
template<bool BN>
__global__ __launch_bounds__(256) void gemm_bf(
    const ushort* __restrict__ Abf, const float* __restrict__ Afp,
    const float* __restrict__ scale, const float* __restrict__ shift,
    const ushort* __restrict__ Bt, float* __restrict__ C,
    int lda, int ldb, int ldc, int kchunk)
{
    __shared__ ushort As[64 * 72];
    __shared__ ushort Bs[64 * 72];
    const int tid  = threadIdx.x;
    const int lane = tid & 63;
    const int wave = tid >> 6;
    const int wy = wave >> 1, wx = wave & 1;
    const int quad = lane >> 4, l16 = lane & 15;
    const int mBase = blockIdx.y * 64;
    const int nBase = blockIdx.x * 64;
    const int kBeg  = blockIdx.z * kchunk;

    f32x4 acc[2][2] = {};

    for (int ks = kBeg; ks < kBeg + kchunk; ks += 64) {
        if (BN) {
            #pragma unroll
            for (int p = 0; p < 4; p++) {
                const int c = p * 256 + tid, r = c >> 4, q = c & 15;
                float4 v  = *(const float4*)&Afp[(size_t)(mBase + r) * lda + ks + q * 4];
                float4 sc = *(const float4*)&scale[ks + q * 4];
                float4 sh = *(const float4*)&shift[ks + q * 4];
                ushort4 o;
                o.x = f2bf(fmaxf(fmaf(v.x, sc.x, sh.x), 0.f));
                o.y = f2bf(fmaxf(fmaf(v.y, sc.y, sh.y), 0.f));
                o.z = f2bf(fmaxf(fmaf(v.z, sc.z, sh.z), 0.f));
                o.w = f2bf(fmaxf(fmaf(v.w, sc.w, sh.w), 0.f));
                *(ushort4*)&As[r * 72 + q * 4] = o;
            }
        } else {
            #pragma unroll
            for (int p = 0; p < 2; p++) {
                const int c = p * 256 + tid, r = c >> 3, q = c & 7;
                *(bf16x8*)&As[r * 72 + q * 8] =
                    *(const bf16x8*)&Abf[(size_t)(mBase + r) * lda + ks + q * 8];
            }
        }
        #pragma unroll
        for (int p = 0; p < 2; p++) {
            const int c = p * 256 + tid, r = c >> 3, q = c & 7;
            *(bf16x8*)&Bs[r * 72 + q * 8] =
                *(const bf16x8*)&Bt[(size_t)(nBase + r) * ldb + ks + q * 8];
        }
        __syncthreads();
        #pragma unroll
        for (int kt = 0; kt < 64; kt += 32) {
            bf16x8 af[2], bfr[2];
            #pragma unroll
            for (int mi = 0; mi < 2; mi++)
                af[mi] = *(bf16x8*)&As[(wy * 32 + mi * 16 + l16) * 72 + kt + quad * 8];
            #pragma unroll
            for (int ni = 0; ni < 2; ni++)
                bfr[ni] = *(bf16x8*)&Bs[(wx * 32 + ni * 16 + l16) * 72 + kt + quad * 8];
            #pragma unroll
            for (int mi = 0; mi < 2; mi++)
                #pragma unroll
                for (int ni = 0; ni < 2; ni++)
                    acc[mi][ni] = __builtin_amdgcn_mfma_f32_16x16x32_bf16(
                        af[mi], bfr[ni], acc[mi][ni], 0, 0, 0);
        }
        __syncthreads();
    }
    #pragma unroll
    for (int mi = 0; mi < 2; mi++)
        #pragma unroll
        for (int ni = 0; ni < 2; ni++)
            #pragma unroll
            for (int e = 0; e < 4; e++) {
                const int gm = mBase + wy * 32 + mi * 16 + quad * 4 + e;
                const int gn = nBase + wx * 32 + ni * 16 + l16;
                unsafeAtomicAdd(&C[(size_t)gm * ldc + gn], acc[mi][ni][e]);
            }
}

// ---- column stats + last-block finalize -> scale/shift ----
__global__ __launch_bounds__(256) void colstats_fin(
    const float* __restrict__ X, float* __restrict__ sum, float* __restrict__ sq,
    unsigned* __restrict__ ticket, const float* __restrict__ g,
    const float* __restrict__ bt, float* __restrict__ scale,
    float* __restrict__ shift)
{
    const int c = threadIdx.x;
    const int r0 = blockIdx.x * 4;
    float s = 0.f, q = 0.f;
    #pragma unroll
    for (int r = r0; r < r0 + 4; ++r) {
        float v = X[r * HID + c];
        s += v;
        q = fmaf(v, v, q);
    }
    unsafeAtomicAdd(&sum[c], s);
    unsafeAtomicAdd(&sq[c], q);
    __threadfence();
    __syncthreads();
    __shared__ int last;
    if (c == 0) last = (atomicAdd(ticket, 1u) == 255u) ? 1 : 0;
    __syncthreads();
    if (last) {
        float s2 = atomicAdd(&sum[c], 0.f);   // device-coherent read
        float q2 = atomicAdd(&sq[c], 0.f);
        float m   = s2 * (1.f / 1024.f);
        float var = fmaf(-m, m, q2 * (1.f / 1024.f));
        float sc  = g[c] * rsqrtf(var + 1e-5f);
        scale[c] = sc;
        shift[c] = fmaf(-sc, m, bt[c]);
    }
}

// ---- fused all-pairs edge network + node update (BN2 on the fly) ----
__global__ __launch_bounds__(256) void pair_update(
    const float* __restrict__ x2, const float* __restrict__ hic,
    const float* __restrict__ scale2, const float* __restrict__ shift2,
    const float* __restrict__ bwe1, const float* __restrict__ We2,
    const float* __restrict__ bwe2, const int* __restrict__ labels,
    float* __restrict__ out)
{
    __shared__ int   slab[N_PTS];
    __shared__ float sacc[4][HID];
    __shared__ float swsum[4];
    const int i = blockIdx.x;
    const int tid = threadIdx.x;
    const int lane = tid & 63;
    const int wave = tid >> 6;

    for (int t = tid; t < N_PTS; t += 256) slab[t] = labels[t];
    __syncthreads();

    const int myLab = slab[i];
    float4 hv_i = *(const float4*)&hic[(size_t)i * 512 + lane * 4];
    float4 bw   = ((const float4*)bwe1)[lane];
    float4 w2   = ((const float4*)We2)[lane];
    float4 sc   = ((const float4*)scale2)[lane];
    float4 sh   = ((const float4*)shift2)[lane];
    const float hb0 = hv_i.x + bw.x, hb1 = hv_i.y + bw.y;
    const float hb2 = hv_i.z + bw.z, hb3 = hv_i.w + bw.w;
    const float b2 = bwe2[0];

    float a0 = 0.f, a1 = 0.f, a2 = 0.f, a3 = 0.f, wsum = 0.f;

    for (int chunk = wave * 64; chunk < N_PTS; chunk += 256) {
        const int j = chunk + lane;
        const bool match = (slab[j] == myLab) && (j != i);
        unsigned long long mask = __ballot(match);
        while (mask) {
            const int b0 = __builtin_ctzll(mask);
            mask &= mask - 1;
            const int jj0 = chunk + b0;
            const bool dual = (mask != 0ull);
            int jj1 = jj0;
            if (dual) {
                const int b1 = __builtin_ctzll(mask);
                mask &= mask - 1;
                jj1 = chunk + b1;
            }
            float4 hv0 = *(const float4*)&hic[(size_t)jj0 * 512 + 256 + lane * 4];
            float4 hv1 = *(const float4*)&hic[(size_t)jj1 * 512 + 256 + lane * 4];
            float p0 = fmaxf(hb0 + hv0.x, 0.f) * w2.x
                     + fmaxf(hb1 + hv0.y, 0.f) * w2.y
                     + fmaxf(hb2 + hv0.z, 0.f) * w2.z
                     + fmaxf(hb3 + hv0.w, 0.f) * w2.w;
            float p1 = fmaxf(hb0 + hv1.x, 0.f) * w2.x
                     + fmaxf(hb1 + hv1.y, 0.f) * w2.y
                     + fmaxf(hb2 + hv1.z, 0.f) * w2.z
                     + fmaxf(hb3 + hv1.w, 0.f) * w2.w;
            #pragma unroll
            for (int off = 1; off < 64; off <<= 1) {
                p0 += __shfl_xor(p0, off, 64);
                p1 += __shfl_xor(p1, off, 64);
            }
            const float w0 = 1.f / (1.f + expf(-(p0 + b2)));
            const float w1 = dual ? 1.f / (1.f + expf(-(p1 + b2))) : 0.f;
            float4 xv0 = *(const float4*)&x2[(size_t)jj0 * HID + lane * 4];
            float4 xv1 = *(const float4*)&x2[(size_t)jj1 * HID + lane * 4];
            float d00 = fmaxf(fmaf(xv0.x, sc.x, sh.x), 0.f);
            float d01 = fmaxf(fmaf(xv0.y, sc.y, sh.y), 0.f);
            float d02 = fmaxf(fmaf(xv0.z, sc.z, sh.z), 0.f);
            float d03 = fmaxf(fmaf(xv0.w, sc.w, sh.w), 0.f);
            float d10 = fmaxf(fmaf(xv1.x, sc.x, sh.x), 0.f);
            float d11 = fmaxf(fmaf(xv1.y, sc.y, sh.y), 0.f);
            float d12 = fmaxf(fmaf(xv1.z, sc.z, sh.z), 0.f);
            float d13 = fmaxf(fmaf(xv1.w, sc.w, sh.w), 0.f);
            a0 = fmaf(w0, d00, fmaf(w1, d10, a0));
            a1 = fmaf(w0, d01, fmaf(w1, d11, a1));
            a2 = fmaf(w0, d02, fmaf(w1, d12, a2));
            a3 = fmaf(w0, d03, fmaf(w1, d13, a3));
            wsum += w0 + w1;
        }
    }
    ((float4*)sacc[wave])[lane] = make_float4(a0, a1, a2, a3);
    if (lane == 0) swsum[wave] = wsum;
    __syncthreads();

    const float at = sacc[0][tid] + sacc[1][tid] + sacc[2][tid] + sacc[3][tid];
    const float wt = swsum[0] + swsum[1] + swsum[2] + swsum[3];
    const float di_i = fmaxf(fmaf(x2[(size_t)i * HID + tid], scale2[tid], shift2[tid]), 0.f);
    out[(size_t)i * HID + tid] = di_i + (wt > 0.f ? at / wt : 0.f);
}

extern "C" void kernel_launch(void* const* d_in, const int* in_sizes, int n_in,
                              void* d_out, int out_size, void* d_ws, size_t ws_size,
                              hipStream_t stream)
{
    const float* features = (const float*)d_in[0];
    const int*   labels   = (const int*)d_in[1];
    const float* W1   = (const float*)d_in[2];
    // b1/b2 cancel exactly through train-mode BN (mean subtraction)
    const float* g1   = (const float*)d_in[4];
    const float* bt1  = (const float*)d_in[5];
    const float* W2   = (const float*)d_in[6];
    const float* g2   = (const float*)d_in[8];
    const float* bt2  = (const float*)d_in[9];
    const float* We1  = (const float*)d_in[10];
    const float* bwe1 = (const float*)d_in[11];
    const float* We2  = (const float*)d_in[12];
    const float* bwe2 = (const float*)d_in[13];
    float* out = (float*)d_out;

    float* ws = (float*)d_ws;
    float*  x1     = ws;                       // 262144 floats
    float*  x2     = ws + 262144;              // 262144
    float*  hic    = ws + 524288;              // 524288 (hi | hj, ldc=512)
    float*  stats  = ws + 1048576;             // 2560 (sums/sq/scale/shift + tickets)
    float*  sum1 = stats,        *sq1 = stats + 256;
    float*  scale1 = stats + 512, *shift1 = stats + 768;
    float*  sum2 = stats + 1024, *sq2 = stats + 1280;
    float*  scale2 = stats + 1536, *shift2 = stats + 1792;
    unsigned* tickets = (unsigned*)(stats + 2048);
    ushort* featbf = (ushort*)(ws + 1051136);  // 2M bf16
    ushort* Wt1    = (ushort*)(ws + 2099712);  // 256x2048 bf16
    ushort* Wt2    = (ushort*)(ws + 2361856);  // 256x256 bf16
    ushort* Wt34   = (ushort*)(ws + 2394624);  // 512x256 bf16

    dim3 blk(256);
    // convert features -> bf16; zero x1/x2/hic + stats region
    prep_a<<<2049, blk, 0, stream>>>(features, featbf, ws, stats);
    // transpose+convert W1, W2, We1 (both halves) -> [n][k] bf16
    prep_t<<<176, blk, 0, stream>>>(W1, W2, We1, Wt1, Wt2, Wt34);
    // x1 = features @ W1  (8-way split-K)
    gemm_bf<false><<<dim3(4, 16, 8), blk, 0, stream>>>(
        featbf, nullptr, nullptr, nullptr, Wt1, x1, FEAT, FEAT, HID, 256);
    colstats_fin<<<256, blk, 0, stream>>>(x1, sum1, sq1, tickets, g1, bt1,
                                          scale1, shift1);
    // x2 = bn_relu(x1) @ W2  (BN fused in A-staging, 4-way split-K)
    gemm_bf<true><<<dim3(4, 16, 4), blk, 0, stream>>>(
        nullptr, x1, scale1, shift1, Wt2, x2, HID, HID, HID, 64);
    colstats_fin<<<256, blk, 0, stream>>>(x2, sum2, sq2, tickets + 1, g2, bt2,
                                          scale2, shift2);
    // hic = bn_relu(x2) @ [We1_top | We1_bot]  (N=512, BN fused)
    gemm_bf<true><<<dim3(8, 16, 4), blk, 0, stream>>>(
        nullptr, x2, scale2, shift2, Wt34, hic, HID, HID, 512, 64);
    // fused all-pairs edge weights + node feature update (BN2 on the fly)
    pair_update<<<N_PTS, blk, 0, stream>>>(x2, hic, scale2, shift2,
                                           bwe1, We2, bwe2, labels, out);
}